// Round 1
// baseline (718.802 us; speedup 1.0000x reference)
//
#include <hip/hip_runtime.h>
#include <cstdint>
#include <cstddef>

// OVOLinearSemanticExtractor (last_only=1) — exact fp32 replication.
// R5: (1) workspace layout transposed to [n][pixel][66] so conv stores are
//     thread-contiguous and fuse_vote staging reads 264B runs (float2).
// (2) fuse_vote LDS tiles in compact float4-group layout -> ds_read_b128
//     taps, 4 outputs per read (792 b32 -> ~200 b128 per thread).
// (3) fuse_vote main loop o-chunk 2->4: streamed scalar weight loads,
//     4 independent FMA chains. FP32 chain order per o unchanged.
// (4) conv2 -> acc[66]-per-thread kernel (1x x traffic, 1:66 load:FMA).
// (5) conv0/conv1 -> 64-thread blocks, more og-groups (1408/3072 blocks)
//     for latency hiding; x re-reads are L3-resident.

#define N_BATCH 8
#define N_OVO   66
#define N_CLS   12

__constant__ unsigned char PAIR_I[N_OVO] = {
  0,0,0,0,0,0,0,0,0,0,0,
  1,1,1,1,1,1,1,1,1,1,
  2,2,2,2,2,2,2,2,2,
  3,3,3,3,3,3,3,3,
  4,4,4,4,4,4,4,
  5,5,5,5,5,5,
  6,6,6,6,6,
  7,7,7,7,
  8,8,8,
  9,9,
  10
};
__constant__ unsigned char PAIR_J[N_OVO] = {
  1,2,3,4,5,6,7,8,9,10,11,
  2,3,4,5,6,7,8,9,10,11,
  3,4,5,6,7,8,9,10,11,
  4,5,6,7,8,9,10,11,
  5,6,7,8,9,10,11,
  6,7,8,9,10,11,
  7,8,9,10,11,
  8,9,10,11,
  9,10,11,
  10,11,
  11
};

// ---------------------------------------------------------------------------
// og-split conv 1x1 (for stage0/stage1): 64-thread blocks for many blocks,
// OG outputs/thread, scalar weights, strict ascending-c fp32 chain.
// Output layout: [n][pixel][66].
// ---------------------------------------------------------------------------
template<int C, int S2, int OG>
__global__ __launch_bounds__(64)
void conv1x1_og(const float* __restrict__ x, const float* __restrict__ w,
                const float* __restrict__ b, float* __restrict__ out)
{
    const int o0 = blockIdx.x * OG;               // uniform -> scalar weights
    const int p  = blockIdx.y * 64 + threadIdx.x;
    const int n  = blockIdx.z;

    float acc[OG];
#pragma unroll
    for (int oi = 0; oi < OG; ++oi) acc[oi] = 0.0f;

    const float* xb = x + (size_t)n * C * S2 + p;
#pragma unroll 4
    for (int c0 = 0; c0 < C; c0 += 8) {
        float xr[8];
#pragma unroll
        for (int k = 0; k < 8; ++k)
            xr[k] = xb[(size_t)(c0 + k) * S2];
#pragma unroll
        for (int oi = 0; oi < OG; ++oi) {
            const float* wrow = w + (size_t)(o0 + oi) * C + c0;
#pragma unroll
            for (int k = 0; k < 8; ++k)
                acc[oi] = __fmaf_rn(wrow[k], xr[k], acc[oi]);
        }
    }

    float* op = out + ((size_t)n * S2 + p) * N_OVO + o0;
#pragma unroll
    for (int oi = 0; oi < OG; ++oi)
        op[oi] = __fadd_rn(acc[oi], b[o0 + oi]);
}

// ---------------------------------------------------------------------------
// all-66 conv 1x1 (for stage2): each thread owns one pixel, all 66 outputs.
// x read exactly once; weights streamed as s_load_dwordx16 per output row.
// ---------------------------------------------------------------------------
template<int C, int S2, int KC>
__global__ __launch_bounds__(256, 4)
void conv1x1_all(const float* __restrict__ x, const float* __restrict__ w,
                 const float* __restrict__ b, float* __restrict__ out)
{
    const int p = blockIdx.x * 256 + threadIdx.x;
    const int n = blockIdx.y;

    float acc[N_OVO];
#pragma unroll
    for (int o = 0; o < N_OVO; ++o) acc[o] = 0.0f;

    const float* xb = x + (size_t)n * C * S2 + p;
#pragma unroll 1
    for (int c0 = 0; c0 < C; c0 += KC) {
        float xr[KC];
#pragma unroll
        for (int k = 0; k < KC; ++k)
            xr[k] = xb[(size_t)(c0 + k) * S2];
#pragma unroll
        for (int o = 0; o < N_OVO; ++o) {
            const float* wrow = w + (size_t)o * C + c0;
#pragma unroll
            for (int k = 0; k < KC; ++k)
                acc[o] = __fmaf_rn(wrow[k], xr[k], acc[o]);
        }
    }

    float* op = out + ((size_t)n * S2 + p) * N_OVO;
#pragma unroll
    for (int o2 = 0; o2 < 33; ++o2) {
        float2 v;
        v.x = __fadd_rn(acc[2 * o2],     b[2 * o2]);
        v.y = __fadd_rn(acc[2 * o2 + 1], b[2 * o2 + 1]);
        *reinterpret_cast<float2*>(op + 2 * o2) = v;
    }
}

// ---------------------------------------------------------------------------
// Fused stage: compact float4-group LDS tiles + b128 tap reads, o-chunk=4.
// ---------------------------------------------------------------------------
#define WT0 4
#define WT1 6
#define WT2 10

// LDS layout per tile (RELS = WT*WT):
//   o in [0,64): slot = (o>>2)*RELS*4 + rel*4 + (o&3)   (float4 per (g,rel))
//   o in {64,65}: slot = 64*RELS + rel*2 + (o-64)        (float2 tail)
// Total floats = RELS*66 (no padding; b128 reads are 16B-aligned).

template<int WT, int SS>
__device__ __forceinline__ void stage_tile(float* __restrict__ t,
                                           const float* __restrict__ src,
                                           int y0, int x0)
{
    constexpr int RELS = WT * WT;
    for (int idx = threadIdx.x; idx < RELS * 33; idx += 256) {
        int r  = idx / 33;
        int k  = idx - r * 33;          // float2 index over o: o = 2k, 2k+1
        int ry = r / WT, rx = r - ry * WT;
        int sy = min(max(y0 + ry, 0), SS - 1);
        int sx = min(max(x0 + rx, 0), SS - 1);
        const float2 v = *reinterpret_cast<const float2*>(
            src + ((size_t)sy * SS + sx) * N_OVO + 2 * k);
        int dst = (k < 32) ? ((k >> 1) * (RELS * 4) + r * 4 + (k & 1) * 2)
                           : (64 * RELS + r * 2);
        *reinterpret_cast<float2*>(t + dst) = v;
    }
}

__device__ __forceinline__ float bil1(float v00, float v01, float v10, float v11,
                                      float wy, float wy0, float wx, float wx0,
                                      int ysing, int xsing)
{
    float u0 = ysing ? v00 : __fmaf_rn(wy, v10, __fmul_rn(wy0, v00));
    float u1 = ysing ? v01 : __fmaf_rn(wy, v11, __fmul_rn(wy0, v01));
    return xsing ? u0 : __fmaf_rn(wx, u1, __fmul_rn(wx0, u0));
}

template<int RELS>
__device__ __forceinline__ float4 bil4(const float* __restrict__ t, int g,
                                       int r00, int r01, int r10, int r11,
                                       float wy, float wx, int ysing, int xsing)
{
    const float* base = t + g * (RELS * 4);
    float4 v00 = *reinterpret_cast<const float4*>(base + r00 * 4);
    float4 v01 = *reinterpret_cast<const float4*>(base + r01 * 4);
    float4 v10 = *reinterpret_cast<const float4*>(base + r10 * 4);
    float4 v11 = *reinterpret_cast<const float4*>(base + r11 * 4);
    float wy0 = 1.0f - wy, wx0 = 1.0f - wx;
    float4 r;
    r.x = bil1(v00.x, v01.x, v10.x, v11.x, wy, wy0, wx, wx0, ysing, xsing);
    r.y = bil1(v00.y, v01.y, v10.y, v11.y, wy, wy0, wx, wx0, ysing, xsing);
    r.z = bil1(v00.z, v01.z, v10.z, v11.z, wy, wy0, wx, wx0, ysing, xsing);
    r.w = bil1(v00.w, v01.w, v10.w, v11.w, wy, wy0, wx, wx0, ysing, xsing);
    return r;
}

__global__ __launch_bounds__(256, 4)   // 40128B LDS + ~124 unified regs -> 4 blocks/CU
void fuse_vote(const float* __restrict__ x3, const float* __restrict__ w3,
               const float* __restrict__ b3,
               const float* __restrict__ c0buf, const float* __restrict__ c1buf,
               const float* __restrict__ c2buf,
               float* __restrict__ out)
{
    const int n  = blockIdx.z;
    const int tx = threadIdx.x & 15, ty = threadIdx.x >> 4;
    const int X0 = blockIdx.x * 16,  Y0 = blockIdx.y * 16;
    const int X  = X0 + tx,          Y  = Y0 + ty;

    __shared__ alignas(16) float t0s[16  * N_OVO];
    __shared__ alignas(16) float t1s[36  * N_OVO];
    __shared__ alignas(16) float t2s[100 * N_OVO];   // 40128 B total

    // ---- per-thread taps (identical float math to the passing kernel) ----
    int rel00[3], rel01[3], rel10[3], rel11[3], ysing[3], xsing[3];
    float wxv[3], wyv[3];
    int x0raw[3], y0raw[3];
    const int   Ss[3]   = {32, 64, 128};
    const float invs[3] = {32.0f / 256.0f, 64.0f / 256.0f, 128.0f / 256.0f};
    const int   Wt[3]   = {WT0, WT1, WT2};
#pragma unroll
    for (int s = 0; s < 3; ++s) {
        float inv = invs[s];
        int S = Ss[s];
        x0raw[s] = (int)floorf(((float)X0 + 0.5f) * inv - 0.5f);
        y0raw[s] = (int)floorf(((float)Y0 + 0.5f) * inv - 0.5f);
        float fx = ((float)X + 0.5f) * inv - 0.5f;
        float fy = ((float)Y + 0.5f) * inv - 0.5f;
        int ix0 = (int)floorf(fx), iy0 = (int)floorf(fy);
        wxv[s] = fx - (float)ix0;  wyv[s] = fy - (float)iy0;
        xsing[s] = (ix0 < 0) || (ix0 + 1 > S - 1);
        ysing[s] = (iy0 < 0) || (iy0 + 1 > S - 1);
        int rx = ix0 - x0raw[s], ry = iy0 - y0raw[s];
        rel00[s] = ry * Wt[s] + rx;
        rel01[s] = rel00[s] + 1;
        rel10[s] = rel00[s] + Wt[s];
        rel11[s] = rel10[s] + 1;
    }

    // ---- cooperative staging from [n][pixel][66] buffers (float2 runs) ----
    stage_tile<WT0, 32 >(t0s, c0buf + (size_t)n * 1024  * N_OVO, y0raw[0], x0raw[0]);
    stage_tile<WT1, 64 >(t1s, c1buf + (size_t)n * 4096  * N_OVO, y0raw[1], x0raw[1]);
    stage_tile<WT2, 128>(t2s, c2buf + (size_t)n * 16384 * N_OVO, y0raw[2], x0raw[2]);

    // stage3 channel column, coalesced; resident across the whole loop
    float xr[64];
    {
        const float* xp = x3 + (size_t)n * 64 * 65536 + (size_t)Y * 256 + X;
#pragma unroll
        for (int c = 0; c < 64; ++c) xr[c] = xp[(size_t)c * 65536];
    }

    __syncthreads();

    unsigned long long packed = 0;   // 12 classes x 4-bit counts (max 11)

#pragma unroll 1
    for (int g = 0; g < 16; ++g) {
        const int o = g * 4;
        // four independent strict c-ascending fp32 FMA chains (scalar weights)
        float a0 = 0.0f, a1 = 0.0f, a2 = 0.0f, a3 = 0.0f;
        const float* wr0 = w3 + (size_t)o * 64;
        const float* wr1 = wr0 + 64;
        const float* wr2 = wr0 + 128;
        const float* wr3 = wr0 + 192;
#pragma unroll
        for (int c = 0; c < 64; ++c) {
            a0 = __fmaf_rn(wr0[c], xr[c], a0);
            a1 = __fmaf_rn(wr1[c], xr[c], a1);
            a2 = __fmaf_rn(wr2[c], xr[c], a2);
            a3 = __fmaf_rn(wr3[c], xr[c], a3);
        }
        float4 L3;
        L3.x = __fadd_rn(a0, b3[o]);
        L3.y = __fadd_rn(a1, b3[o + 1]);
        L3.z = __fadd_rn(a2, b3[o + 2]);
        L3.w = __fadd_rn(a3, b3[o + 3]);

        float4 s0 = bil4<16 >(t0s, g, rel00[0], rel01[0], rel10[0], rel11[0],
                              wyv[0], wxv[0], ysing[0], xsing[0]);
        float4 s1 = bil4<36 >(t1s, g, rel00[1], rel01[1], rel10[1], rel11[1],
                              wyv[1], wxv[1], ysing[1], xsing[1]);
        float4 s2 = bil4<100>(t2s, g, rel00[2], rel01[2], rel10[2], rel11[2],
                              wyv[2], wxv[2], ysing[2], xsing[2]);

        // reference order: ((L0 + L1) + L2) + L3
        float v0 = __fadd_rn(__fadd_rn(__fadd_rn(s0.x, s1.x), s2.x), L3.x);
        float v1 = __fadd_rn(__fadd_rn(__fadd_rn(s0.y, s1.y), s2.y), L3.y);
        float v2 = __fadd_rn(__fadd_rn(__fadd_rn(s0.z, s1.z), s2.z), L3.z);
        float v3 = __fadd_rn(__fadd_rn(__fadd_rn(s0.w, s1.w), s2.w), L3.w);

        packed += (v0 > 0.0f) ? (1ull << (4 * (int)PAIR_I[o]))
                              : (1ull << (4 * (int)PAIR_J[o]));
        packed += (v1 > 0.0f) ? (1ull << (4 * (int)PAIR_I[o + 1]))
                              : (1ull << (4 * (int)PAIR_J[o + 1]));
        packed += (v2 > 0.0f) ? (1ull << (4 * (int)PAIR_I[o + 2]))
                              : (1ull << (4 * (int)PAIR_J[o + 2]));
        packed += (v3 > 0.0f) ? (1ull << (4 * (int)PAIR_I[o + 3]))
                              : (1ull << (4 * (int)PAIR_J[o + 3]));
    }

    // tail: o = 64, 65 (float2 region of each tile)
    {
        float a0 = 0.0f, a1 = 0.0f;
        const float* wr0 = w3 + (size_t)64 * 64;
        const float* wr1 = wr0 + 64;
#pragma unroll
        for (int c = 0; c < 64; ++c) {
            a0 = __fmaf_rn(wr0[c], xr[c], a0);
            a1 = __fmaf_rn(wr1[c], xr[c], a1);
        }
        float L3a = __fadd_rn(a0, b3[64]);
        float L3b = __fadd_rn(a1, b3[65]);

        float La[3], Lb[3];
#pragma unroll
        for (int s = 0; s < 3; ++s) {
            const float* t = (s == 0) ? t0s : (s == 1) ? t1s : t2s;
            const int RELS = Wt[s] * Wt[s];
            const float* tb = t + 64 * RELS;
            float2 v00 = *reinterpret_cast<const float2*>(tb + rel00[s] * 2);
            float2 v01 = *reinterpret_cast<const float2*>(tb + rel01[s] * 2);
            float2 v10 = *reinterpret_cast<const float2*>(tb + rel10[s] * 2);
            float2 v11 = *reinterpret_cast<const float2*>(tb + rel11[s] * 2);
            float wy = wyv[s], wx = wxv[s];
            float wy0 = 1.0f - wy, wx0 = 1.0f - wx;
            La[s] = bil1(v00.x, v01.x, v10.x, v11.x, wy, wy0, wx, wx0, ysing[s], xsing[s]);
            Lb[s] = bil1(v00.y, v01.y, v10.y, v11.y, wy, wy0, wx, wx0, ysing[s], xsing[s]);
        }
        float ta = __fadd_rn(__fadd_rn(__fadd_rn(La[0], La[1]), La[2]), L3a);
        float tb = __fadd_rn(__fadd_rn(__fadd_rn(Lb[0], Lb[1]), Lb[2]), L3b);
        packed += (ta > 0.0f) ? (1ull << (4 * (int)PAIR_I[64]))
                              : (1ull << (4 * (int)PAIR_J[64]));
        packed += (tb > 0.0f) ? (1ull << (4 * (int)PAIR_I[65]))
                              : (1ull << (4 * (int)PAIR_J[65]));
    }

    float* op = out + (size_t)n * N_CLS * 65536 + (size_t)Y * 256 + X;
#pragma unroll
    for (int k = 0; k < N_CLS; ++k)
        op[(size_t)k * 65536] = (float)(int)((packed >> (4 * k)) & 15ull);
}

// ---------------------------------------------------------------------------
extern "C" void kernel_launch(void* const* d_in, const int* in_sizes, int n_in,
                              void* d_out, int out_size, void* d_ws, size_t ws_size,
                              hipStream_t stream)
{
    const float* stage0 = (const float*)d_in[0];
    const float* w0     = (const float*)d_in[1];
    const float* b0     = (const float*)d_in[2];
    const float* stage1 = (const float*)d_in[3];
    const float* w1     = (const float*)d_in[4];
    const float* b1     = (const float*)d_in[5];
    const float* stage2 = (const float*)d_in[6];
    const float* w2     = (const float*)d_in[7];
    const float* b2     = (const float*)d_in[8];
    const float* stage3 = (const float*)d_in[9];
    const float* w3     = (const float*)d_in[10];
    const float* b3     = (const float*)d_in[11];
    float* out = (float*)d_out;

    // fp32 workspace, NEW layout [n][pixel][66]:
    // c0 8*1024*66, c1 8*4096*66, c2 8*16384*66  (45.4 MB total, same as R4)
    float* c0 = (float*)d_ws;
    float* c1 = c0 + (size_t)540672;
    float* c2 = c1 + (size_t)2162688;

    // conv0: 11 og-groups x 16 px-blocks x 8 = 1408 blocks (was 192)
    conv1x1_og<512, 1024, 6><<<dim3(11, 16, N_BATCH), 64, 0, stream>>>(stage0, w0, b0, c0);
    // conv1: 6 og-groups x 64 px-blocks x 8 = 3072 blocks (was 768)
    conv1x1_og<256, 4096, 11><<<dim3(6, 64, N_BATCH), 64, 0, stream>>>(stage1, w1, b1, c1);
    // conv2: all-66 per thread, x read exactly once (was 6x)
    conv1x1_all<128, 16384, 16><<<dim3(64, N_BATCH), 256, 0, stream>>>(stage2, w2, b2, c2);

    fuse_vote<<<dim3(16, 16, N_BATCH), 256, 0, stream>>>(stage3, w3, b3, c0, c1, c2, out);
}

// Round 2
// 486.966 us; speedup vs baseline: 1.4761x; 1.4761x over previous
//
#include <hip/hip_runtime.h>
#include <cstdint>
#include <cstddef>

// OVOLinearSemanticExtractor (last_only=1) — exact fp32 replication.
// R6: merge the three 1x1 convs into ONE launch (4032 blocks co-scheduled)
//     using the proven R4 og-split body (OG=11 -> 88 weight dwords per
//     c-chunk fits the SGPR file; conv1x1_all's 1056-dword unroll was
//     SMEM-serialized at 2 blocks/CU -> 232 us). Output layout [n][p][66]
//     kept for fuse_vote's float2 staging. fuse_vote unchanged from R5.

#define N_BATCH 8
#define N_OVO   66
#define N_CLS   12

__constant__ unsigned char PAIR_I[N_OVO] = {
  0,0,0,0,0,0,0,0,0,0,0,
  1,1,1,1,1,1,1,1,1,1,
  2,2,2,2,2,2,2,2,2,
  3,3,3,3,3,3,3,3,
  4,4,4,4,4,4,4,
  5,5,5,5,5,5,
  6,6,6,6,6,
  7,7,7,7,
  8,8,8,
  9,9,
  10
};
__constant__ unsigned char PAIR_J[N_OVO] = {
  1,2,3,4,5,6,7,8,9,10,11,
  2,3,4,5,6,7,8,9,10,11,
  3,4,5,6,7,8,9,10,11,
  4,5,6,7,8,9,10,11,
  5,6,7,8,9,10,11,
  6,7,8,9,10,11,
  7,8,9,10,11,
  8,9,10,11,
  9,10,11,
  10,11,
  11
};

// ---------------------------------------------------------------------------
// og-split conv 1x1 body (proven R4 structure): 256 px/block, OG=11 outputs
// per thread, scalar (SGPR) weights, strict ascending-c fp32 FMA chain.
// Writes [n][pixel][66].
// ---------------------------------------------------------------------------
template<int C, int S2, int OG>
__device__ __forceinline__
void conv_body(int b, const float* __restrict__ x, const float* __restrict__ w,
               const float* __restrict__ bias, float* __restrict__ out)
{
    constexpr int NOG = N_OVO / OG;          // 6
    constexpr int PX  = S2 / 256;
    const int og  = b % NOG;                 // fastest -> L2 x-window reuse
    int rest      = b / NOG;
    const int pxb = rest % PX;
    const int n   = rest / PX;
    const int o0  = og * OG;                 // block-uniform -> scalar weights
    const int p   = pxb * 256 + threadIdx.x;

    float acc[OG];
#pragma unroll
    for (int oi = 0; oi < OG; ++oi) acc[oi] = 0.0f;

    const float* xb = x + (size_t)n * C * S2 + p;
    for (int c0 = 0; c0 < C; c0 += 8) {
        float xr[8];
#pragma unroll
        for (int k = 0; k < 8; ++k)
            xr[k] = xb[(size_t)(c0 + k) * S2];
#pragma unroll
        for (int oi = 0; oi < OG; ++oi) {
            const float* wrow = w + (size_t)(o0 + oi) * C + c0;
#pragma unroll
            for (int k = 0; k < 8; ++k)
                acc[oi] = __fmaf_rn(wrow[k], xr[k], acc[oi]);
        }
    }

    float* op = out + ((size_t)n * S2 + p) * N_OVO + o0;
#pragma unroll
    for (int oi = 0; oi < OG; ++oi)
        op[oi] = __fadd_rn(acc[oi], bias[o0 + oi]);
}

// Merged conv dispatch: blocks [0,192) stage0, [192,960) stage1,
// [960,4032) stage2. All three stages co-resident -> no serial underfill.
#define B0 192
#define B1 768
#define B2 3072

__global__ __launch_bounds__(256)
void conv_all(const float* __restrict__ x0, const float* __restrict__ w0,
              const float* __restrict__ b0, float* __restrict__ c0,
              const float* __restrict__ x1, const float* __restrict__ w1,
              const float* __restrict__ b1, float* __restrict__ c1,
              const float* __restrict__ x2, const float* __restrict__ w2,
              const float* __restrict__ b2, float* __restrict__ c2)
{
    const int bid = blockIdx.x;
    if (bid < B0) {
        conv_body<512, 1024, 11>(bid, x0, w0, b0, c0);
    } else if (bid < B0 + B1) {
        conv_body<256, 4096, 11>(bid - B0, x1, w1, b1, c1);
    } else {
        conv_body<128, 16384, 11>(bid - (B0 + B1), x2, w2, b2, c2);
    }
}

// ---------------------------------------------------------------------------
// Fused stage (unchanged from R5): compact float4-group LDS tiles + b128 tap
// reads, o-chunk=4, packed nibble vote.
// ---------------------------------------------------------------------------
#define WT0 4
#define WT1 6
#define WT2 10

template<int WT, int SS>
__device__ __forceinline__ void stage_tile(float* __restrict__ t,
                                           const float* __restrict__ src,
                                           int y0, int x0)
{
    constexpr int RELS = WT * WT;
    for (int idx = threadIdx.x; idx < RELS * 33; idx += 256) {
        int r  = idx / 33;
        int k  = idx - r * 33;          // float2 index over o: o = 2k, 2k+1
        int ry = r / WT, rx = r - ry * WT;
        int sy = min(max(y0 + ry, 0), SS - 1);
        int sx = min(max(x0 + rx, 0), SS - 1);
        const float2 v = *reinterpret_cast<const float2*>(
            src + ((size_t)sy * SS + sx) * N_OVO + 2 * k);
        int dst = (k < 32) ? ((k >> 1) * (RELS * 4) + r * 4 + (k & 1) * 2)
                           : (64 * RELS + r * 2);
        *reinterpret_cast<float2*>(t + dst) = v;
    }
}

__device__ __forceinline__ float bil1(float v00, float v01, float v10, float v11,
                                      float wy, float wy0, float wx, float wx0,
                                      int ysing, int xsing)
{
    float u0 = ysing ? v00 : __fmaf_rn(wy, v10, __fmul_rn(wy0, v00));
    float u1 = ysing ? v01 : __fmaf_rn(wy, v11, __fmul_rn(wy0, v01));
    return xsing ? u0 : __fmaf_rn(wx, u1, __fmul_rn(wx0, u0));
}

template<int RELS>
__device__ __forceinline__ float4 bil4(const float* __restrict__ t, int g,
                                       int r00, int r01, int r10, int r11,
                                       float wy, float wx, int ysing, int xsing)
{
    const float* base = t + g * (RELS * 4);
    float4 v00 = *reinterpret_cast<const float4*>(base + r00 * 4);
    float4 v01 = *reinterpret_cast<const float4*>(base + r01 * 4);
    float4 v10 = *reinterpret_cast<const float4*>(base + r10 * 4);
    float4 v11 = *reinterpret_cast<const float4*>(base + r11 * 4);
    float wy0 = 1.0f - wy, wx0 = 1.0f - wx;
    float4 r;
    r.x = bil1(v00.x, v01.x, v10.x, v11.x, wy, wy0, wx, wx0, ysing, xsing);
    r.y = bil1(v00.y, v01.y, v10.y, v11.y, wy, wy0, wx, wx0, ysing, xsing);
    r.z = bil1(v00.z, v01.z, v10.z, v11.z, wy, wy0, wx, wx0, ysing, xsing);
    r.w = bil1(v00.w, v01.w, v10.w, v11.w, wy, wy0, wx, wx0, ysing, xsing);
    return r;
}

__global__ __launch_bounds__(256, 4)
void fuse_vote(const float* __restrict__ x3, const float* __restrict__ w3,
               const float* __restrict__ b3,
               const float* __restrict__ c0buf, const float* __restrict__ c1buf,
               const float* __restrict__ c2buf,
               float* __restrict__ out)
{
    const int n  = blockIdx.z;
    const int tx = threadIdx.x & 15, ty = threadIdx.x >> 4;
    const int X0 = blockIdx.x * 16,  Y0 = blockIdx.y * 16;
    const int X  = X0 + tx,          Y  = Y0 + ty;

    __shared__ alignas(16) float t0s[16  * N_OVO];
    __shared__ alignas(16) float t1s[36  * N_OVO];
    __shared__ alignas(16) float t2s[100 * N_OVO];   // 40128 B total

    int rel00[3], rel01[3], rel10[3], rel11[3], ysing[3], xsing[3];
    float wxv[3], wyv[3];
    int x0raw[3], y0raw[3];
    const int   Ss[3]   = {32, 64, 128};
    const float invs[3] = {32.0f / 256.0f, 64.0f / 256.0f, 128.0f / 256.0f};
    const int   Wt[3]   = {WT0, WT1, WT2};
#pragma unroll
    for (int s = 0; s < 3; ++s) {
        float inv = invs[s];
        int S = Ss[s];
        x0raw[s] = (int)floorf(((float)X0 + 0.5f) * inv - 0.5f);
        y0raw[s] = (int)floorf(((float)Y0 + 0.5f) * inv - 0.5f);
        float fx = ((float)X + 0.5f) * inv - 0.5f;
        float fy = ((float)Y + 0.5f) * inv - 0.5f;
        int ix0 = (int)floorf(fx), iy0 = (int)floorf(fy);
        wxv[s] = fx - (float)ix0;  wyv[s] = fy - (float)iy0;
        xsing[s] = (ix0 < 0) || (ix0 + 1 > S - 1);
        ysing[s] = (iy0 < 0) || (iy0 + 1 > S - 1);
        int rx = ix0 - x0raw[s], ry = iy0 - y0raw[s];
        rel00[s] = ry * Wt[s] + rx;
        rel01[s] = rel00[s] + 1;
        rel10[s] = rel00[s] + Wt[s];
        rel11[s] = rel10[s] + 1;
    }

    stage_tile<WT0, 32 >(t0s, c0buf + (size_t)n * 1024  * N_OVO, y0raw[0], x0raw[0]);
    stage_tile<WT1, 64 >(t1s, c1buf + (size_t)n * 4096  * N_OVO, y0raw[1], x0raw[1]);
    stage_tile<WT2, 128>(t2s, c2buf + (size_t)n * 16384 * N_OVO, y0raw[2], x0raw[2]);

    float xr[64];
    {
        const float* xp = x3 + (size_t)n * 64 * 65536 + (size_t)Y * 256 + X;
#pragma unroll
        for (int c = 0; c < 64; ++c) xr[c] = xp[(size_t)c * 65536];
    }

    __syncthreads();

    unsigned long long packed = 0;   // 12 classes x 4-bit counts (max 11)

#pragma unroll 1
    for (int g = 0; g < 16; ++g) {
        const int o = g * 4;
        float a0 = 0.0f, a1 = 0.0f, a2 = 0.0f, a3 = 0.0f;
        const float* wr0 = w3 + (size_t)o * 64;
        const float* wr1 = wr0 + 64;
        const float* wr2 = wr0 + 128;
        const float* wr3 = wr0 + 192;
#pragma unroll
        for (int c = 0; c < 64; ++c) {
            a0 = __fmaf_rn(wr0[c], xr[c], a0);
            a1 = __fmaf_rn(wr1[c], xr[c], a1);
            a2 = __fmaf_rn(wr2[c], xr[c], a2);
            a3 = __fmaf_rn(wr3[c], xr[c], a3);
        }
        float4 L3;
        L3.x = __fadd_rn(a0, b3[o]);
        L3.y = __fadd_rn(a1, b3[o + 1]);
        L3.z = __fadd_rn(a2, b3[o + 2]);
        L3.w = __fadd_rn(a3, b3[o + 3]);

        float4 s0 = bil4<16 >(t0s, g, rel00[0], rel01[0], rel10[0], rel11[0],
                              wyv[0], wxv[0], ysing[0], xsing[0]);
        float4 s1 = bil4<36 >(t1s, g, rel00[1], rel01[1], rel10[1], rel11[1],
                              wyv[1], wxv[1], ysing[1], xsing[1]);
        float4 s2 = bil4<100>(t2s, g, rel00[2], rel01[2], rel10[2], rel11[2],
                              wyv[2], wxv[2], ysing[2], xsing[2]);

        float v0 = __fadd_rn(__fadd_rn(__fadd_rn(s0.x, s1.x), s2.x), L3.x);
        float v1 = __fadd_rn(__fadd_rn(__fadd_rn(s0.y, s1.y), s2.y), L3.y);
        float v2 = __fadd_rn(__fadd_rn(__fadd_rn(s0.z, s1.z), s2.z), L3.z);
        float v3 = __fadd_rn(__fadd_rn(__fadd_rn(s0.w, s1.w), s2.w), L3.w);

        packed += (v0 > 0.0f) ? (1ull << (4 * (int)PAIR_I[o]))
                              : (1ull << (4 * (int)PAIR_J[o]));
        packed += (v1 > 0.0f) ? (1ull << (4 * (int)PAIR_I[o + 1]))
                              : (1ull << (4 * (int)PAIR_J[o + 1]));
        packed += (v2 > 0.0f) ? (1ull << (4 * (int)PAIR_I[o + 2]))
                              : (1ull << (4 * (int)PAIR_J[o + 2]));
        packed += (v3 > 0.0f) ? (1ull << (4 * (int)PAIR_I[o + 3]))
                              : (1ull << (4 * (int)PAIR_J[o + 3]));
    }

    // tail: o = 64, 65 (float2 region of each tile)
    {
        float a0 = 0.0f, a1 = 0.0f;
        const float* wr0 = w3 + (size_t)64 * 64;
        const float* wr1 = wr0 + 64;
#pragma unroll
        for (int c = 0; c < 64; ++c) {
            a0 = __fmaf_rn(wr0[c], xr[c], a0);
            a1 = __fmaf_rn(wr1[c], xr[c], a1);
        }
        float L3a = __fadd_rn(a0, b3[64]);
        float L3b = __fadd_rn(a1, b3[65]);

        float La[3], Lb[3];
#pragma unroll
        for (int s = 0; s < 3; ++s) {
            const float* t = (s == 0) ? t0s : (s == 1) ? t1s : t2s;
            const int RELS = Wt[s] * Wt[s];
            const float* tb = t + 64 * RELS;
            float2 v00 = *reinterpret_cast<const float2*>(tb + rel00[s] * 2);
            float2 v01 = *reinterpret_cast<const float2*>(tb + rel01[s] * 2);
            float2 v10 = *reinterpret_cast<const float2*>(tb + rel10[s] * 2);
            float2 v11 = *reinterpret_cast<const float2*>(tb + rel11[s] * 2);
            float wy = wyv[s], wx = wxv[s];
            float wy0 = 1.0f - wy, wx0 = 1.0f - wx;
            La[s] = bil1(v00.x, v01.x, v10.x, v11.x, wy, wy0, wx, wx0, ysing[s], xsing[s]);
            Lb[s] = bil1(v00.y, v01.y, v10.y, v11.y, wy, wy0, wx, wx0, ysing[s], xsing[s]);
        }
        float ta = __fadd_rn(__fadd_rn(__fadd_rn(La[0], La[1]), La[2]), L3a);
        float tb = __fadd_rn(__fadd_rn(__fadd_rn(Lb[0], Lb[1]), Lb[2]), L3b);
        packed += (ta > 0.0f) ? (1ull << (4 * (int)PAIR_I[64]))
                              : (1ull << (4 * (int)PAIR_J[64]));
        packed += (tb > 0.0f) ? (1ull << (4 * (int)PAIR_I[65]))
                              : (1ull << (4 * (int)PAIR_J[65]));
    }

    float* op = out + (size_t)n * N_CLS * 65536 + (size_t)Y * 256 + X;
#pragma unroll
    for (int k = 0; k < N_CLS; ++k)
        op[(size_t)k * 65536] = (float)(int)((packed >> (4 * k)) & 15ull);
}

// ---------------------------------------------------------------------------
extern "C" void kernel_launch(void* const* d_in, const int* in_sizes, int n_in,
                              void* d_out, int out_size, void* d_ws, size_t ws_size,
                              hipStream_t stream)
{
    const float* stage0 = (const float*)d_in[0];
    const float* w0     = (const float*)d_in[1];
    const float* b0     = (const float*)d_in[2];
    const float* stage1 = (const float*)d_in[3];
    const float* w1     = (const float*)d_in[4];
    const float* b1     = (const float*)d_in[5];
    const float* stage2 = (const float*)d_in[6];
    const float* w2     = (const float*)d_in[7];
    const float* b2     = (const float*)d_in[8];
    const float* stage3 = (const float*)d_in[9];
    const float* w3     = (const float*)d_in[10];
    const float* b3     = (const float*)d_in[11];
    float* out = (float*)d_out;

    // fp32 workspace, layout [n][pixel][66]:
    // c0 8*1024*66, c1 8*4096*66, c2 8*16384*66  (45.4 MB total)
    float* c0 = (float*)d_ws;
    float* c1 = c0 + (size_t)540672;
    float* c2 = c1 + (size_t)2162688;

    // single merged conv launch: 192 + 768 + 3072 = 4032 blocks co-scheduled
    conv_all<<<dim3(B0 + B1 + B2), 256, 0, stream>>>(
        stage0, w0, b0, c0,
        stage1, w1, b1, c1,
        stage2, w2, b2, c2);

    fuse_vote<<<dim3(16, 16, N_BATCH), 256, 0, stream>>>(stage3, w3, b3, c0, c1, c2, out);
}

// Round 4
// 484.648 us; speedup vs baseline: 1.4831x; 1.0048x over previous
//
#include <hip/hip_runtime.h>
#include <cstdint>
#include <cstddef>

// OVOLinearSemanticExtractor (last_only=1) — exact fp32 replication.
// R8 = R7 with the OOB fix: w3t moved from d_ws+45.4MB (past the proven
// workspace footprint -> suspected page fault -> container failure) into a
// static __device__ array. Workspace layout identical to passing R6.
// R7 changes kept:
//  - fuse_vote stage3 conv is c-outer with acc[66] in VGPRs; weights read
//    from transposed w3t[c][66] -> contiguous uniform 264B scalar loads per
//    c, no AGPR xr churn, no per-g SMEM bursts.
//  - __syncthreads moved AFTER the conv phase: LDS staging latency hides
//    under 4224 FMAs.
//  - phase B fully unrolled (ds_read base+immediate) with range-safe XOR
//    swizzle slot = rel ^ ((rel>>3)&3) to break rel/rel+8 bank aliasing
//    (R6: 4.08M conflict cycles).
// Per-o FMA chains keep exact ascending-c order -> bit-exact.

#define N_BATCH 8
#define N_OVO   66
#define N_CLS   12

__constant__ unsigned char PAIR_I[N_OVO] = {
  0,0,0,0,0,0,0,0,0,0,0,
  1,1,1,1,1,1,1,1,1,1,
  2,2,2,2,2,2,2,2,2,
  3,3,3,3,3,3,3,3,
  4,4,4,4,4,4,4,
  5,5,5,5,5,5,
  6,6,6,6,6,
  7,7,7,7,
  8,8,8,
  9,9,
  10
};
__constant__ unsigned char PAIR_J[N_OVO] = {
  1,2,3,4,5,6,7,8,9,10,11,
  2,3,4,5,6,7,8,9,10,11,
  3,4,5,6,7,8,9,10,11,
  4,5,6,7,8,9,10,11,
  5,6,7,8,9,10,11,
  6,7,8,9,10,11,
  7,8,9,10,11,
  8,9,10,11,
  9,10,11,
  10,11,
  11
};

// transposed stage3 weights [c][66] — static device allocation (NOT in d_ws)
__device__ float W3T[64 * N_OVO];

// ---------------------------------------------------------------------------
// og-split conv 1x1 body (proven): 256 px/block, OG=11 outputs per thread,
// scalar (SGPR) weights, strict ascending-c fp32 FMA chain. Writes [n][p][66].
// ---------------------------------------------------------------------------
template<int C, int S2, int OG>
__device__ __forceinline__
void conv_body(int b, const float* __restrict__ x, const float* __restrict__ w,
               const float* __restrict__ bias, float* __restrict__ out)
{
    constexpr int NOG = N_OVO / OG;          // 6
    constexpr int PX  = S2 / 256;
    const int og  = b % NOG;                 // fastest -> L2 x-window reuse
    int rest      = b / NOG;
    const int pxb = rest % PX;
    const int n   = rest / PX;
    const int o0  = og * OG;                 // block-uniform -> scalar weights
    const int p   = pxb * 256 + threadIdx.x;

    float acc[OG];
#pragma unroll
    for (int oi = 0; oi < OG; ++oi) acc[oi] = 0.0f;

    const float* xb = x + (size_t)n * C * S2 + p;
    for (int c0 = 0; c0 < C; c0 += 8) {
        float xr[8];
#pragma unroll
        for (int k = 0; k < 8; ++k)
            xr[k] = xb[(size_t)(c0 + k) * S2];
#pragma unroll
        for (int oi = 0; oi < OG; ++oi) {
            const float* wrow = w + (size_t)(o0 + oi) * C + c0;
#pragma unroll
            for (int k = 0; k < 8; ++k)
                acc[oi] = __fmaf_rn(wrow[k], xr[k], acc[oi]);
        }
    }

    float* op = out + ((size_t)n * S2 + p) * N_OVO + o0;
#pragma unroll
    for (int oi = 0; oi < OG; ++oi)
        op[oi] = __fadd_rn(acc[oi], bias[o0 + oi]);
}

// Merged conv dispatch + w3 transpose block.
#define B0 192
#define B1 768
#define B2 3072

__global__ __launch_bounds__(256)
void conv_all(const float* __restrict__ x0, const float* __restrict__ w0,
              const float* __restrict__ b0, float* __restrict__ c0,
              const float* __restrict__ x1, const float* __restrict__ w1,
              const float* __restrict__ b1, float* __restrict__ c1,
              const float* __restrict__ x2, const float* __restrict__ w2,
              const float* __restrict__ b2, float* __restrict__ c2,
              const float* __restrict__ w3)
{
    const int bid = blockIdx.x;
    if (bid < B0) {
        conv_body<512, 1024, 11>(bid, x0, w0, b0, c0);
    } else if (bid < B0 + B1) {
        conv_body<256, 4096, 11>(bid - B0, x1, w1, b1, c1);
    } else if (bid < B0 + B1 + B2) {
        conv_body<128, 16384, 11>(bid - (B0 + B1), x2, w2, b2, c2);
    } else {
        // transpose w3 [66][64] -> W3T [64][66]
        for (int idx = threadIdx.x; idx < 64 * N_OVO; idx += 256) {
            int c = idx / N_OVO; int o = idx - c * N_OVO;
            W3T[idx] = w3[o * 64 + c];
        }
    }
}

// ---------------------------------------------------------------------------
// Fused stage.
// ---------------------------------------------------------------------------
#define WT0 4
#define WT1 6
#define WT2 10

// LDS layout per tile (RELS = WT*WT):
//   o in [0,64): 16B slot index = (o>>2)*RELS + swz(rel), element (o&3)
//     with swz(rel) = rel ^ ((rel>>3)&3)   (involution within 4-slot groups,
//     always in-range since RELS % 4 == 0; breaks rel/rel+8 bank aliasing)
//   o in {64,65}: float2 tail at 64*RELS + rel*2 + (o-64)

template<int WT, int SS>
__device__ __forceinline__ void stage_tile(float* __restrict__ t,
                                           const float* __restrict__ src,
                                           int y0, int x0)
{
    constexpr int RELS = WT * WT;
    for (int idx = threadIdx.x; idx < RELS * 33; idx += 256) {
        int r  = idx / 33;
        int k  = idx - r * 33;          // float2 index over o: o = 2k, 2k+1
        int ry = r / WT, rx = r - ry * WT;
        int sy = min(max(y0 + ry, 0), SS - 1);
        int sx = min(max(x0 + rx, 0), SS - 1);
        const float2 v = *reinterpret_cast<const float2*>(
            src + ((size_t)sy * SS + sx) * N_OVO + 2 * k);
        int dst;
        if (k < 32) {
            int sr = r ^ ((r >> 3) & 3);
            dst = ((k >> 1) * RELS + sr) * 4 + (k & 1) * 2;
        } else {
            dst = 64 * RELS + r * 2;
        }
        *reinterpret_cast<float2*>(t + dst) = v;
    }
}

__device__ __forceinline__ float bil1(float v00, float v01, float v10, float v11,
                                      float wy, float wy0, float wx, float wx0,
                                      int ysing, int xsing)
{
    float u0 = ysing ? v00 : __fmaf_rn(wy, v10, __fmul_rn(wy0, v00));
    float u1 = ysing ? v01 : __fmaf_rn(wy, v11, __fmul_rn(wy0, v01));
    return xsing ? u0 : __fmaf_rn(wx, u1, __fmul_rn(wx0, u0));
}

template<int RELS>
__device__ __forceinline__ float4 bil4(const float* __restrict__ t, int g,
                                       int s00, int s01, int s10, int s11,
                                       float wy, float wx, int ysing, int xsing)
{
    const float* base = t + g * (RELS * 4);
    float4 v00 = *reinterpret_cast<const float4*>(base + s00 * 4);
    float4 v01 = *reinterpret_cast<const float4*>(base + s01 * 4);
    float4 v10 = *reinterpret_cast<const float4*>(base + s10 * 4);
    float4 v11 = *reinterpret_cast<const float4*>(base + s11 * 4);
    float wy0 = 1.0f - wy, wx0 = 1.0f - wx;
    float4 r;
    r.x = bil1(v00.x, v01.x, v10.x, v11.x, wy, wy0, wx, wx0, ysing, xsing);
    r.y = bil1(v00.y, v01.y, v10.y, v11.y, wy, wy0, wx, wx0, ysing, xsing);
    r.z = bil1(v00.z, v01.z, v10.z, v11.z, wy, wy0, wx, wx0, ysing, xsing);
    r.w = bil1(v00.w, v01.w, v10.w, v11.w, wy, wy0, wx, wx0, ysing, xsing);
    return r;
}

__global__ __launch_bounds__(256, 4)   // 128 VGPR cap: acc[66]+taps fit
void fuse_vote(const float* __restrict__ x3,
               const float* __restrict__ b3,
               const float* __restrict__ c0buf, const float* __restrict__ c1buf,
               const float* __restrict__ c2buf,
               float* __restrict__ out)
{
    const int n  = blockIdx.z;
    const int tx = threadIdx.x & 15, ty = threadIdx.x >> 4;
    const int X0 = blockIdx.x * 16,  Y0 = blockIdx.y * 16;
    const int X  = X0 + tx,          Y  = Y0 + ty;

    __shared__ alignas(16) float t0s[16  * N_OVO];
    __shared__ alignas(16) float t1s[36  * N_OVO];
    __shared__ alignas(16) float t2s[100 * N_OVO];   // 40128 B total

    // ---- per-thread taps (identical float math to the passing kernel) ----
    int rel00[3], rel01[3], rel10[3], rel11[3], ysing[3], xsing[3];
    int s00[3], s01[3], s10[3], s11[3];               // swizzled slots
    float wxv[3], wyv[3];
    int x0raw[3], y0raw[3];
    const int   Ss[3]   = {32, 64, 128};
    const float invs[3] = {32.0f / 256.0f, 64.0f / 256.0f, 128.0f / 256.0f};
    const int   Wt[3]   = {WT0, WT1, WT2};
#pragma unroll
    for (int s = 0; s < 3; ++s) {
        float inv = invs[s];
        int S = Ss[s];
        x0raw[s] = (int)floorf(((float)X0 + 0.5f) * inv - 0.5f);
        y0raw[s] = (int)floorf(((float)Y0 + 0.5f) * inv - 0.5f);
        float fx = ((float)X + 0.5f) * inv - 0.5f;
        float fy = ((float)Y + 0.5f) * inv - 0.5f;
        int ix0 = (int)floorf(fx), iy0 = (int)floorf(fy);
        wxv[s] = fx - (float)ix0;  wyv[s] = fy - (float)iy0;
        xsing[s] = (ix0 < 0) || (ix0 + 1 > S - 1);
        ysing[s] = (iy0 < 0) || (iy0 + 1 > S - 1);
        int rx = ix0 - x0raw[s], ry = iy0 - y0raw[s];
        rel00[s] = ry * Wt[s] + rx;
        rel01[s] = rel00[s] + 1;
        rel10[s] = rel00[s] + Wt[s];
        rel11[s] = rel10[s] + 1;
        s00[s] = rel00[s] ^ ((rel00[s] >> 3) & 3);
        s01[s] = rel01[s] ^ ((rel01[s] >> 3) & 3);
        s10[s] = rel10[s] ^ ((rel10[s] >> 3) & 3);
        s11[s] = rel11[s] ^ ((rel11[s] >> 3) & 3);
    }

    // ---- cooperative staging (LDS writes; consumed after the conv phase) ----
    stage_tile<WT0, 32 >(t0s, c0buf + (size_t)n * 1024  * N_OVO, y0raw[0], x0raw[0]);
    stage_tile<WT1, 64 >(t1s, c1buf + (size_t)n * 4096  * N_OVO, y0raw[1], x0raw[1]);
    stage_tile<WT2, 128>(t2s, c2buf + (size_t)n * 16384 * N_OVO, y0raw[2], x0raw[2]);

    // ---- phase A: stage3 conv, c-outer, acc[66] in VGPRs ----
    // Each o's chain is still ascending-c with init 0 -> bit-exact.
    float acc[N_OVO];
#pragma unroll
    for (int o = 0; o < N_OVO; ++o) acc[o] = 0.0f;

    {
        const float* xp = x3 + (size_t)n * 64 * 65536 + (size_t)Y * 256 + X;
#pragma unroll 4
        for (int c = 0; c < 64; ++c) {
            float xv = xp[(size_t)c * 65536];
            const float* wc = W3T + c * N_OVO;   // uniform -> scalar loads
#pragma unroll
            for (int o = 0; o < N_OVO; ++o)
                acc[o] = __fmaf_rn(wc[o], xv, acc[o]);
        }
    }

    __syncthreads();   // staging guaranteed complete; hid under 4224 FMAs

    unsigned long long packed = 0;   // 12 classes x 4-bit counts (max 11)

#pragma unroll
    for (int g = 0; g < 16; ++g) {
        const int o = g * 4;
        float4 L3;
        L3.x = __fadd_rn(acc[o],     b3[o]);
        L3.y = __fadd_rn(acc[o + 1], b3[o + 1]);
        L3.z = __fadd_rn(acc[o + 2], b3[o + 2]);
        L3.w = __fadd_rn(acc[o + 3], b3[o + 3]);

        float4 s0 = bil4<16 >(t0s, g, s00[0], s01[0], s10[0], s11[0],
                              wyv[0], wxv[0], ysing[0], xsing[0]);
        float4 s1 = bil4<36 >(t1s, g, s00[1], s01[1], s10[1], s11[1],
                              wyv[1], wxv[1], ysing[1], xsing[1]);
        float4 s2 = bil4<100>(t2s, g, s00[2], s01[2], s10[2], s11[2],
                              wyv[2], wxv[2], ysing[2], xsing[2]);

        // reference order: ((L0 + L1) + L2) + L3
        float v0 = __fadd_rn(__fadd_rn(__fadd_rn(s0.x, s1.x), s2.x), L3.x);
        float v1 = __fadd_rn(__fadd_rn(__fadd_rn(s0.y, s1.y), s2.y), L3.y);
        float v2 = __fadd_rn(__fadd_rn(__fadd_rn(s0.z, s1.z), s2.z), L3.z);
        float v3 = __fadd_rn(__fadd_rn(__fadd_rn(s0.w, s1.w), s2.w), L3.w);

        packed += (v0 > 0.0f) ? (1ull << (4 * (int)PAIR_I[o]))
                              : (1ull << (4 * (int)PAIR_J[o]));
        packed += (v1 > 0.0f) ? (1ull << (4 * (int)PAIR_I[o + 1]))
                              : (1ull << (4 * (int)PAIR_J[o + 1]));
        packed += (v2 > 0.0f) ? (1ull << (4 * (int)PAIR_I[o + 2]))
                              : (1ull << (4 * (int)PAIR_J[o + 2]));
        packed += (v3 > 0.0f) ? (1ull << (4 * (int)PAIR_I[o + 3]))
                              : (1ull << (4 * (int)PAIR_J[o + 3]));
    }

    // tail: o = 64, 65 (float2 region, unswizzled rel)
    {
        float L3a = __fadd_rn(acc[64], b3[64]);
        float L3b = __fadd_rn(acc[65], b3[65]);

        float La[3], Lb[3];
#pragma unroll
        for (int s = 0; s < 3; ++s) {
            const float* t = (s == 0) ? t0s : (s == 1) ? t1s : t2s;
            const int RELS = Wt[s] * Wt[s];
            const float* tb = t + 64 * RELS;
            float2 v00 = *reinterpret_cast<const float2*>(tb + rel00[s] * 2);
            float2 v01 = *reinterpret_cast<const float2*>(tb + rel01[s] * 2);
            float2 v10 = *reinterpret_cast<const float2*>(tb + rel10[s] * 2);
            float2 v11 = *reinterpret_cast<const float2*>(tb + rel11[s] * 2);
            float wy = wyv[s], wx = wxv[s];
            float wy0 = 1.0f - wy, wx0 = 1.0f - wx;
            La[s] = bil1(v00.x, v01.x, v10.x, v11.x, wy, wy0, wx, wx0, ysing[s], xsing[s]);
            Lb[s] = bil1(v00.y, v01.y, v10.y, v11.y, wy, wy0, wx, wx0, ysing[s], xsing[s]);
        }
        float ta = __fadd_rn(__fadd_rn(__fadd_rn(La[0], La[1]), La[2]), L3a);
        float tb = __fadd_rn(__fadd_rn(__fadd_rn(Lb[0], Lb[1]), Lb[2]), L3b);
        packed += (ta > 0.0f) ? (1ull << (4 * (int)PAIR_I[64]))
                              : (1ull << (4 * (int)PAIR_J[64]));
        packed += (tb > 0.0f) ? (1ull << (4 * (int)PAIR_I[65]))
                              : (1ull << (4 * (int)PAIR_J[65]));
    }

    float* op = out + (size_t)n * N_CLS * 65536 + (size_t)Y * 256 + X;
#pragma unroll
    for (int k = 0; k < N_CLS; ++k)
        op[(size_t)k * 65536] = (float)(int)((packed >> (4 * k)) & 15ull);
}

// ---------------------------------------------------------------------------
extern "C" void kernel_launch(void* const* d_in, const int* in_sizes, int n_in,
                              void* d_out, int out_size, void* d_ws, size_t ws_size,
                              hipStream_t stream)
{
    const float* stage0 = (const float*)d_in[0];
    const float* w0     = (const float*)d_in[1];
    const float* b0     = (const float*)d_in[2];
    const float* stage1 = (const float*)d_in[3];
    const float* w1     = (const float*)d_in[4];
    const float* b1     = (const float*)d_in[5];
    const float* stage2 = (const float*)d_in[6];
    const float* w2     = (const float*)d_in[7];
    const float* b2     = (const float*)d_in[8];
    const float* stage3 = (const float*)d_in[9];
    const float* w3     = (const float*)d_in[10];
    const float* b3     = (const float*)d_in[11];
    float* out = (float*)d_out;

    // fp32 workspace, layout [n][pixel][66] — EXACTLY the proven 45.4 MB:
    // c0 8*1024*66, c1 8*4096*66, c2 8*16384*66. (W3T is a __device__ global.)
    float* c0 = (float*)d_ws;
    float* c1 = c0 + (size_t)540672;
    float* c2 = c1 + (size_t)2162688;

    // merged conv launch: 192 + 768 + 3072 conv blocks + 1 transpose block
    conv_all<<<dim3(B0 + B1 + B2 + 1), 256, 0, stream>>>(
        stage0, w0, b0, c0,
        stage1, w1, b1, c1,
        stage2, w2, b2, c2,
        w3);

    fuse_vote<<<dim3(16, 16, N_BATCH), 256, 0, stream>>>(stage3, b3, c0, c1, c2, out);
}

// Round 5
// 478.216 us; speedup vs baseline: 1.5031x; 1.0134x over previous
//
#include <hip/hip_runtime.h>
#include <cstdint>
#include <cstddef>

// OVOLinearSemanticExtractor (last_only=1) — exact fp32 replication.
// R9 = R8 with ONE change: fuse_vote __launch_bounds__(256,4) -> (256,3).
// R8's c-outer acc[66] spilled to scratch (WRITE_SIZE 25->174MB) because the
// 128-unified-reg cap can't hold acc[66] in AGPRs (R6's xr[64] fit exactly).
// (256,3) allows ~170 unified regs -> acc[66] goes to AGPRs, no spill.
// Occupancy unchanged: LDS 40.4KB already limits to 3 blocks/CU.
// conv_all deliberately untouched so it tops the next profile (need counters).

#define N_BATCH 8
#define N_OVO   66
#define N_CLS   12

__constant__ unsigned char PAIR_I[N_OVO] = {
  0,0,0,0,0,0,0,0,0,0,0,
  1,1,1,1,1,1,1,1,1,1,
  2,2,2,2,2,2,2,2,2,
  3,3,3,3,3,3,3,3,
  4,4,4,4,4,4,4,
  5,5,5,5,5,5,
  6,6,6,6,6,
  7,7,7,7,
  8,8,8,
  9,9,
  10
};
__constant__ unsigned char PAIR_J[N_OVO] = {
  1,2,3,4,5,6,7,8,9,10,11,
  2,3,4,5,6,7,8,9,10,11,
  3,4,5,6,7,8,9,10,11,
  4,5,6,7,8,9,10,11,
  5,6,7,8,9,10,11,
  6,7,8,9,10,11,
  7,8,9,10,11,
  8,9,10,11,
  9,10,11,
  10,11,
  11
};

// transposed stage3 weights [c][66] — static device allocation (NOT in d_ws)
__device__ float W3T[64 * N_OVO];

// ---------------------------------------------------------------------------
// og-split conv 1x1 body (proven): 256 px/block, OG=11 outputs per thread,
// scalar (SGPR) weights, strict ascending-c fp32 FMA chain. Writes [n][p][66].
// ---------------------------------------------------------------------------
template<int C, int S2, int OG>
__device__ __forceinline__
void conv_body(int b, const float* __restrict__ x, const float* __restrict__ w,
               const float* __restrict__ bias, float* __restrict__ out)
{
    constexpr int NOG = N_OVO / OG;          // 6
    constexpr int PX  = S2 / 256;
    const int og  = b % NOG;                 // fastest -> L2 x-window reuse
    int rest      = b / NOG;
    const int pxb = rest % PX;
    const int n   = rest / PX;
    const int o0  = og * OG;                 // block-uniform -> scalar weights
    const int p   = pxb * 256 + threadIdx.x;

    float acc[OG];
#pragma unroll
    for (int oi = 0; oi < OG; ++oi) acc[oi] = 0.0f;

    const float* xb = x + (size_t)n * C * S2 + p;
    for (int c0 = 0; c0 < C; c0 += 8) {
        float xr[8];
#pragma unroll
        for (int k = 0; k < 8; ++k)
            xr[k] = xb[(size_t)(c0 + k) * S2];
#pragma unroll
        for (int oi = 0; oi < OG; ++oi) {
            const float* wrow = w + (size_t)(o0 + oi) * C + c0;
#pragma unroll
            for (int k = 0; k < 8; ++k)
                acc[oi] = __fmaf_rn(wrow[k], xr[k], acc[oi]);
        }
    }

    float* op = out + ((size_t)n * S2 + p) * N_OVO + o0;
#pragma unroll
    for (int oi = 0; oi < OG; ++oi)
        op[oi] = __fadd_rn(acc[oi], bias[o0 + oi]);
}

// Merged conv dispatch + w3 transpose block.
#define B0 192
#define B1 768
#define B2 3072

__global__ __launch_bounds__(256)
void conv_all(const float* __restrict__ x0, const float* __restrict__ w0,
              const float* __restrict__ b0, float* __restrict__ c0,
              const float* __restrict__ x1, const float* __restrict__ w1,
              const float* __restrict__ b1, float* __restrict__ c1,
              const float* __restrict__ x2, const float* __restrict__ w2,
              const float* __restrict__ b2, float* __restrict__ c2,
              const float* __restrict__ w3)
{
    const int bid = blockIdx.x;
    if (bid < B0) {
        conv_body<512, 1024, 11>(bid, x0, w0, b0, c0);
    } else if (bid < B0 + B1) {
        conv_body<256, 4096, 11>(bid - B0, x1, w1, b1, c1);
    } else if (bid < B0 + B1 + B2) {
        conv_body<128, 16384, 11>(bid - (B0 + B1), x2, w2, b2, c2);
    } else {
        // transpose w3 [66][64] -> W3T [64][66]
        for (int idx = threadIdx.x; idx < 64 * N_OVO; idx += 256) {
            int c = idx / N_OVO; int o = idx - c * N_OVO;
            W3T[idx] = w3[o * 64 + c];
        }
    }
}

// ---------------------------------------------------------------------------
// Fused stage.
// ---------------------------------------------------------------------------
#define WT0 4
#define WT1 6
#define WT2 10

// LDS layout per tile (RELS = WT*WT):
//   o in [0,64): 16B slot index = (o>>2)*RELS + swz(rel), element (o&3)
//     with swz(rel) = rel ^ ((rel>>3)&3)   (involution within 4-slot groups,
//     always in-range since RELS % 4 == 0)
//   o in {64,65}: float2 tail at 64*RELS + rel*2 + (o-64)

template<int WT, int SS>
__device__ __forceinline__ void stage_tile(float* __restrict__ t,
                                           const float* __restrict__ src,
                                           int y0, int x0)
{
    constexpr int RELS = WT * WT;
    for (int idx = threadIdx.x; idx < RELS * 33; idx += 256) {
        int r  = idx / 33;
        int k  = idx - r * 33;          // float2 index over o: o = 2k, 2k+1
        int ry = r / WT, rx = r - ry * WT;
        int sy = min(max(y0 + ry, 0), SS - 1);
        int sx = min(max(x0 + rx, 0), SS - 1);
        const float2 v = *reinterpret_cast<const float2*>(
            src + ((size_t)sy * SS + sx) * N_OVO + 2 * k);
        int dst;
        if (k < 32) {
            int sr = r ^ ((r >> 3) & 3);
            dst = ((k >> 1) * RELS + sr) * 4 + (k & 1) * 2;
        } else {
            dst = 64 * RELS + r * 2;
        }
        *reinterpret_cast<float2*>(t + dst) = v;
    }
}

__device__ __forceinline__ float bil1(float v00, float v01, float v10, float v11,
                                      float wy, float wy0, float wx, float wx0,
                                      int ysing, int xsing)
{
    float u0 = ysing ? v00 : __fmaf_rn(wy, v10, __fmul_rn(wy0, v00));
    float u1 = ysing ? v01 : __fmaf_rn(wy, v11, __fmul_rn(wy0, v01));
    return xsing ? u0 : __fmaf_rn(wx, u1, __fmul_rn(wx0, u0));
}

template<int RELS>
__device__ __forceinline__ float4 bil4(const float* __restrict__ t, int g,
                                       int s00, int s01, int s10, int s11,
                                       float wy, float wx, int ysing, int xsing)
{
    const float* base = t + g * (RELS * 4);
    float4 v00 = *reinterpret_cast<const float4*>(base + s00 * 4);
    float4 v01 = *reinterpret_cast<const float4*>(base + s01 * 4);
    float4 v10 = *reinterpret_cast<const float4*>(base + s10 * 4);
    float4 v11 = *reinterpret_cast<const float4*>(base + s11 * 4);
    float wy0 = 1.0f - wy, wx0 = 1.0f - wx;
    float4 r;
    r.x = bil1(v00.x, v01.x, v10.x, v11.x, wy, wy0, wx, wx0, ysing, xsing);
    r.y = bil1(v00.y, v01.y, v10.y, v11.y, wy, wy0, wx, wx0, ysing, xsing);
    r.z = bil1(v00.z, v01.z, v10.z, v11.z, wy, wy0, wx, wx0, ysing, xsing);
    r.w = bil1(v00.w, v01.w, v10.w, v11.w, wy, wy0, wx, wx0, ysing, xsing);
    return r;
}

__global__ __launch_bounds__(256, 3)   // ~170 unified regs: acc[66] -> AGPRs, no spill
void fuse_vote(const float* __restrict__ x3,
               const float* __restrict__ b3,
               const float* __restrict__ c0buf, const float* __restrict__ c1buf,
               const float* __restrict__ c2buf,
               float* __restrict__ out)
{
    const int n  = blockIdx.z;
    const int tx = threadIdx.x & 15, ty = threadIdx.x >> 4;
    const int X0 = blockIdx.x * 16,  Y0 = blockIdx.y * 16;
    const int X  = X0 + tx,          Y  = Y0 + ty;

    __shared__ alignas(16) float t0s[16  * N_OVO];
    __shared__ alignas(16) float t1s[36  * N_OVO];
    __shared__ alignas(16) float t2s[100 * N_OVO];   // 40128 B total

    // ---- per-thread taps (identical float math to the passing kernel) ----
    int rel00[3], rel01[3], rel10[3], rel11[3], ysing[3], xsing[3];
    int s00[3], s01[3], s10[3], s11[3];               // swizzled slots
    float wxv[3], wyv[3];
    int x0raw[3], y0raw[3];
    const int   Ss[3]   = {32, 64, 128};
    const float invs[3] = {32.0f / 256.0f, 64.0f / 256.0f, 128.0f / 256.0f};
    const int   Wt[3]   = {WT0, WT1, WT2};
#pragma unroll
    for (int s = 0; s < 3; ++s) {
        float inv = invs[s];
        int S = Ss[s];
        x0raw[s] = (int)floorf(((float)X0 + 0.5f) * inv - 0.5f);
        y0raw[s] = (int)floorf(((float)Y0 + 0.5f) * inv - 0.5f);
        float fx = ((float)X + 0.5f) * inv - 0.5f;
        float fy = ((float)Y + 0.5f) * inv - 0.5f;
        int ix0 = (int)floorf(fx), iy0 = (int)floorf(fy);
        wxv[s] = fx - (float)ix0;  wyv[s] = fy - (float)iy0;
        xsing[s] = (ix0 < 0) || (ix0 + 1 > S - 1);
        ysing[s] = (iy0 < 0) || (iy0 + 1 > S - 1);
        int rx = ix0 - x0raw[s], ry = iy0 - y0raw[s];
        rel00[s] = ry * Wt[s] + rx;
        rel01[s] = rel00[s] + 1;
        rel10[s] = rel00[s] + Wt[s];
        rel11[s] = rel10[s] + 1;
        s00[s] = rel00[s] ^ ((rel00[s] >> 3) & 3);
        s01[s] = rel01[s] ^ ((rel01[s] >> 3) & 3);
        s10[s] = rel10[s] ^ ((rel10[s] >> 3) & 3);
        s11[s] = rel11[s] ^ ((rel11[s] >> 3) & 3);
    }

    // ---- cooperative staging (LDS writes; consumed after the conv phase) ----
    stage_tile<WT0, 32 >(t0s, c0buf + (size_t)n * 1024  * N_OVO, y0raw[0], x0raw[0]);
    stage_tile<WT1, 64 >(t1s, c1buf + (size_t)n * 4096  * N_OVO, y0raw[1], x0raw[1]);
    stage_tile<WT2, 128>(t2s, c2buf + (size_t)n * 16384 * N_OVO, y0raw[2], x0raw[2]);

    // ---- phase A: stage3 conv, c-outer, acc[66] (AGPR-resident) ----
    // Each o's chain is still ascending-c with init 0 -> bit-exact.
    float acc[N_OVO];
#pragma unroll
    for (int o = 0; o < N_OVO; ++o) acc[o] = 0.0f;

    {
        const float* xp = x3 + (size_t)n * 64 * 65536 + (size_t)Y * 256 + X;
#pragma unroll 4
        for (int c = 0; c < 64; ++c) {
            float xv = xp[(size_t)c * 65536];
            const float* wc = W3T + c * N_OVO;   // uniform -> scalar loads
#pragma unroll
            for (int o = 0; o < N_OVO; ++o)
                acc[o] = __fmaf_rn(wc[o], xv, acc[o]);
        }
    }

    __syncthreads();   // staging guaranteed complete; hid under 4224 FMAs

    unsigned long long packed = 0;   // 12 classes x 4-bit counts (max 11)

#pragma unroll
    for (int g = 0; g < 16; ++g) {
        const int o = g * 4;
        float4 L3;
        L3.x = __fadd_rn(acc[o],     b3[o]);
        L3.y = __fadd_rn(acc[o + 1], b3[o + 1]);
        L3.z = __fadd_rn(acc[o + 2], b3[o + 2]);
        L3.w = __fadd_rn(acc[o + 3], b3[o + 3]);

        float4 s0 = bil4<16 >(t0s, g, s00[0], s01[0], s10[0], s11[0],
                              wyv[0], wxv[0], ysing[0], xsing[0]);
        float4 s1 = bil4<36 >(t1s, g, s00[1], s01[1], s10[1], s11[1],
                              wyv[1], wxv[1], ysing[1], xsing[1]);
        float4 s2 = bil4<100>(t2s, g, s00[2], s01[2], s10[2], s11[2],
                              wyv[2], wxv[2], ysing[2], xsing[2]);

        // reference order: ((L0 + L1) + L2) + L3
        float v0 = __fadd_rn(__fadd_rn(__fadd_rn(s0.x, s1.x), s2.x), L3.x);
        float v1 = __fadd_rn(__fadd_rn(__fadd_rn(s0.y, s1.y), s2.y), L3.y);
        float v2 = __fadd_rn(__fadd_rn(__fadd_rn(s0.z, s1.z), s2.z), L3.z);
        float v3 = __fadd_rn(__fadd_rn(__fadd_rn(s0.w, s1.w), s2.w), L3.w);

        packed += (v0 > 0.0f) ? (1ull << (4 * (int)PAIR_I[o]))
                              : (1ull << (4 * (int)PAIR_J[o]));
        packed += (v1 > 0.0f) ? (1ull << (4 * (int)PAIR_I[o + 1]))
                              : (1ull << (4 * (int)PAIR_J[o + 1]));
        packed += (v2 > 0.0f) ? (1ull << (4 * (int)PAIR_I[o + 2]))
                              : (1ull << (4 * (int)PAIR_J[o + 2]));
        packed += (v3 > 0.0f) ? (1ull << (4 * (int)PAIR_I[o + 3]))
                              : (1ull << (4 * (int)PAIR_J[o + 3]));
    }

    // tail: o = 64, 65 (float2 region, unswizzled rel)
    {
        float L3a = __fadd_rn(acc[64], b3[64]);
        float L3b = __fadd_rn(acc[65], b3[65]);

        float La[3], Lb[3];
#pragma unroll
        for (int s = 0; s < 3; ++s) {
            const float* t = (s == 0) ? t0s : (s == 1) ? t1s : t2s;
            const int RELS = Wt[s] * Wt[s];
            const float* tb = t + 64 * RELS;
            float2 v00 = *reinterpret_cast<const float2*>(tb + rel00[s] * 2);
            float2 v01 = *reinterpret_cast<const float2*>(tb + rel01[s] * 2);
            float2 v10 = *reinterpret_cast<const float2*>(tb + rel10[s] * 2);
            float2 v11 = *reinterpret_cast<const float2*>(tb + rel11[s] * 2);
            float wy = wyv[s], wx = wxv[s];
            float wy0 = 1.0f - wy, wx0 = 1.0f - wx;
            La[s] = bil1(v00.x, v01.x, v10.x, v11.x, wy, wy0, wx, wx0, ysing[s], xsing[s]);
            Lb[s] = bil1(v00.y, v01.y, v10.y, v11.y, wy, wy0, wx, wx0, ysing[s], xsing[s]);
        }
        float ta = __fadd_rn(__fadd_rn(__fadd_rn(La[0], La[1]), La[2]), L3a);
        float tb = __fadd_rn(__fadd_rn(__fadd_rn(Lb[0], Lb[1]), Lb[2]), L3b);
        packed += (ta > 0.0f) ? (1ull << (4 * (int)PAIR_I[64]))
                              : (1ull << (4 * (int)PAIR_J[64]));
        packed += (tb > 0.0f) ? (1ull << (4 * (int)PAIR_I[65]))
                              : (1ull << (4 * (int)PAIR_J[65]));
    }

    float* op = out + (size_t)n * N_CLS * 65536 + (size_t)Y * 256 + X;
#pragma unroll
    for (int k = 0; k < N_CLS; ++k)
        op[(size_t)k * 65536] = (float)(int)((packed >> (4 * k)) & 15ull);
}

// ---------------------------------------------------------------------------
extern "C" void kernel_launch(void* const* d_in, const int* in_sizes, int n_in,
                              void* d_out, int out_size, void* d_ws, size_t ws_size,
                              hipStream_t stream)
{
    const float* stage0 = (const float*)d_in[0];
    const float* w0     = (const float*)d_in[1];
    const float* b0     = (const float*)d_in[2];
    const float* stage1 = (const float*)d_in[3];
    const float* w1     = (const float*)d_in[4];
    const float* b1     = (const float*)d_in[5];
    const float* stage2 = (const float*)d_in[6];
    const float* w2     = (const float*)d_in[7];
    const float* b2     = (const float*)d_in[8];
    const float* stage3 = (const float*)d_in[9];
    const float* w3     = (const float*)d_in[10];
    const float* b3     = (const float*)d_in[11];
    float* out = (float*)d_out;

    // fp32 workspace, layout [n][pixel][66] — EXACTLY the proven 45.4 MB:
    // c0 8*1024*66, c1 8*4096*66, c2 8*16384*66. (W3T is a __device__ global.)
    float* c0 = (float*)d_ws;
    float* c1 = c0 + (size_t)540672;
    float* c2 = c1 + (size_t)2162688;

    // merged conv launch: 192 + 768 + 3072 conv blocks + 1 transpose block
    conv_all<<<dim3(B0 + B1 + B2 + 1), 256, 0, stream>>>(
        stage0, w0, b0, c0,
        stage1, w1, b1, c1,
        stage2, w2, b2, c2,
        w3);

    fuse_vote<<<dim3(16, 16, N_BATCH), 256, 0, stream>>>(stage3, b3, c0, c1, c2, out);
}